// Round 2
// baseline (2254.407 us; speedup 1.0000x reference)
//
#include <hip/hip_runtime.h>
#include <math.h>

#define B_    16
#define N_    1024
#define G_    16      // blocks per batch
#define ITERS 100

// ws layout: [cnt: B_*ITERS u32, padded to 8192B][gpart: 2*B_*G_*N_ f32][nug: B_*N_ f32]
#define CNT_BYTES   (B_ * ITERS * 4)
#define GPART_OFF   8192
#define NUG_OFF     (GPART_OFF + 2 * B_ * G_ * N_ * 4)

__device__ __forceinline__ float fast_div(float num, float den) {
    float r = __builtin_amdgcn_rcpf(den);
    r = r * (2.0f - den * r);      // one Newton step -> ~full fp32 accuracy
    return num * r;
}

// 512 threads/block, 1 block/CU (VGPR-limited), 256 blocks = 16 batches x 16.
// Each thread holds a 4-row x 32-contiguous-col tile of U = exp(-C/eps) in
// VGPRs (128 floats). launch_bounds(512,2) -> 256-VGPR budget so the array
// actually promotes (R1's 1024-thread/128-VGPR config spilled: VGPR_Count=56).
__global__ __launch_bounds__(512, 2)
void sinkhorn_kernel(const float* __restrict__ C, float* __restrict__ out,
                     float* __restrict__ gpart, float* __restrict__ nug,
                     unsigned int* __restrict__ cnt)
{
    __shared__ float part[16 * 1024];   // 64 KB: 16 row-group partial slabs
    __shared__ float mu_s[1024];        // 4 KB: current mu (no aliasing)

    const int tid = threadIdx.x;        // 0..511 (8 waves)
    const int w   = tid >> 6;           // wave 0..7
    const int l   = tid & 63;
    const int h   = l >> 5;             // half-wave 0/1
    const int l2  = l & 31;             // lane within half-wave
    // XCD-affinity swizzle: batch b's 16 blocks share bid%8
    const int bid = blockIdx.x;
    const int xx = bid & 7, ss = bid >> 3;
    const int b = xx + ((ss >> 4) << 3);
    const int g = ss & 15;

    const int row0 = 64 * g + 8 * w + 4 * h;  // my 4 rows: row0..row0+3
    const int c0   = 32 * l2;                 // my 32 contiguous cols
    const int slab = 2 * w + h;               // row-group id 0..15
    const float cons = 1.0f / 1024.0f;

    // ---- one-time: load U tile into registers ----
    float u[4][32];
    {
        const float* Cb = C + (size_t)b * N_ * N_ + (size_t)row0 * N_ + c0;
        #pragma unroll
        for (int rr = 0; rr < 4; ++rr) {
            const float4* Cr = (const float4*)(Cb + (size_t)rr * N_);
            #pragma unroll
            for (int q = 0; q < 8; ++q) {
                float4 v = Cr[q];
                u[rr][4*q+0] = expf(-20.0f * v.x);
                u[rr][4*q+1] = expf(-20.0f * v.y);
                u[rr][4*q+2] = expf(-20.0f * v.z);
                u[rr][4*q+3] = expf(-20.0f * v.w);
            }
        }
    }

    if (tid < 512) { // init mu = cons (2 elems/thread)
        ((float2*)mu_s)[tid] = make_float2(cons, cons);
    }
    __syncthreads();

    const float4* mu4 = (const float4*)mu_s;

    for (int it = 0; it < ITERS; ++it) {
        // ---- Phase A: s_i = sum_j U_ij * mu_j over my 32 cols ----
        float mv[32];
        #pragma unroll
        for (int i = 0; i < 8; ++i) {
            float4 m = mu4[l2 * 8 + i];        // ds_read_b128, contiguous
            mv[4*i+0] = m.x; mv[4*i+1] = m.y; mv[4*i+2] = m.z; mv[4*i+3] = m.w;
        }
        float a0 = 0.f, a1 = 0.f, a2 = 0.f, a3 = 0.f;
        #pragma unroll
        for (int k = 0; k < 32; ++k) {
            a0 += u[0][k] * mv[k];
            a1 += u[1][k] * mv[k];
            a2 += u[2][k] * mv[k];
            a3 += u[3][k] * mv[k];
        }
        // reduce across the 32 lanes sharing these rows (5 steps)
        #pragma unroll
        for (int off = 1; off < 32; off <<= 1) {
            a0 += __shfl_xor(a0, off, 64);
            a1 += __shfl_xor(a1, off, 64);
            a2 += __shfl_xor(a2, off, 64);
            a3 += __shfl_xor(a3, off, 64);
        }
        float nu0 = fast_div(cons, a0);
        float nu1 = fast_div(cons, a1);
        float nu2 = fast_div(cons, a2);
        float nu3 = fast_div(cons, a3);

        if (it == ITERS - 1 && l2 < 4) {       // publish final nu
            float nv = nu0;
            if (l2 == 1) nv = nu1;
            if (l2 == 2) nv = nu2;
            if (l2 == 3) nv = nu3;
            nug[b * N_ + row0 + l2] = nv;
        }

        // ---- Phase B: per-row-group col partials -> LDS slab ----
        {
            float4* p4 = (float4*)(part + slab * 1024 + c0);
            #pragma unroll
            for (int i = 0; i < 8; ++i) {
                float4 p;
                p.x = u[0][4*i+0]*nu0 + u[1][4*i+0]*nu1 + u[2][4*i+0]*nu2 + u[3][4*i+0]*nu3;
                p.y = u[0][4*i+1]*nu0 + u[1][4*i+1]*nu1 + u[2][4*i+1]*nu2 + u[3][4*i+1]*nu3;
                p.z = u[0][4*i+2]*nu0 + u[1][4*i+2]*nu1 + u[2][4*i+2]*nu2 + u[3][4*i+2]*nu3;
                p.w = u[0][4*i+3]*nu0 + u[1][4*i+3]*nu1 + u[2][4*i+3]*nu2 + u[3][4*i+3]*nu3;
                p4[i] = p;                      // ds_write_b128
            }
        }
        __syncthreads();   // S1: slabs complete

        // ---- column sums across 16 slabs: thread owns cols 2*tid, 2*tid+1 ----
        const int buf = it & 1;
        {
            const float2* p2 = (const float2*)part;
            float sx = 0.f, sy = 0.f;
            #pragma unroll
            for (int s16 = 0; s16 < 16; ++s16) {
                float2 v = p2[s16 * 512 + tid]; // conflict-free
                sx += v.x; sy += v.y;
            }
            float2* gp2 = (float2*)gpart;
            gp2[(((size_t)buf * B_ + b) * G_ + g) * 512 + tid] = make_float2(sx, sy);
        }

        // ---- device barrier among the 16 blocks of batch b ----
        __syncthreads();   // S2: drains every wave's vmcnt (gpart stores done)
        if (tid == 0) {
            unsigned int* c = &cnt[b * ITERS + it];
            __threadfence();
            __hip_atomic_fetch_add(c, 1u, __ATOMIC_ACQ_REL, __HIP_MEMORY_SCOPE_AGENT);
            while (__hip_atomic_load(c, __ATOMIC_ACQUIRE, __HIP_MEMORY_SCOPE_AGENT) < G_)
                __builtin_amdgcn_s_sleep(2);
            __threadfence();
        }
        __syncthreads();   // S3

        // ---- reduce 16 block-partials -> new mu (redundant per block) ----
        {
            const float2* gp2 = (const float2*)gpart;
            float sx = 0.f, sy = 0.f;
            #pragma unroll
            for (int g2 = 0; g2 < 16; ++g2) {
                float2 v = gp2[(((size_t)buf * B_ + b) * G_ + g2) * 512 + tid];
                sx += v.x; sy += v.y;
            }
            ((float2*)mu_s)[tid] = make_float2(fast_div(cons, sx), fast_div(cons, sy));
        }
        __syncthreads();   // S4: mu_s ready for next phase A
    }

    // ---- epilogue: T_ij = mu_i * U_ij * nu_j ----
    float mu_i[4];
    #pragma unroll
    for (int rr = 0; rr < 4; ++rr)
        mu_i[rr] = mu_s[row0 + rr];

    float nuv[32];
    {
        const float4* nb4 = (const float4*)(nug + b * N_ + c0);
        #pragma unroll
        for (int i = 0; i < 8; ++i) {
            float4 v = nb4[i];
            nuv[4*i+0] = v.x; nuv[4*i+1] = v.y; nuv[4*i+2] = v.z; nuv[4*i+3] = v.w;
        }
    }

    float* ob = out + (size_t)b * N_ * N_ + (size_t)row0 * N_ + c0;
    #pragma unroll
    for (int rr = 0; rr < 4; ++rr) {
        float4* o4 = (float4*)(ob + (size_t)rr * N_);
        #pragma unroll
        for (int i = 0; i < 8; ++i) {
            float4 t;
            t.x = mu_i[rr] * u[rr][4*i+0] * nuv[4*i+0];
            t.y = mu_i[rr] * u[rr][4*i+1] * nuv[4*i+1];
            t.z = mu_i[rr] * u[rr][4*i+2] * nuv[4*i+2];
            t.w = mu_i[rr] * u[rr][4*i+3] * nuv[4*i+3];
            o4[i] = t;
        }
    }
}

extern "C" void kernel_launch(void* const* d_in, const int* in_sizes, int n_in,
                              void* d_out, int out_size, void* d_ws, size_t ws_size,
                              hipStream_t stream) {
    const float* C = (const float*)d_in[2];     // (B, N, N); x,y unused
    float* out = (float*)d_out;

    unsigned char* ws = (unsigned char*)d_ws;
    unsigned int* cnt = (unsigned int*)ws;
    float* gpart = (float*)(ws + GPART_OFF);
    float* nug   = (float*)(ws + NUG_OFF);

    hipMemsetAsync(cnt, 0, CNT_BYTES, stream);  // barrier counters start at 0
    hipLaunchKernelGGL(sinkhorn_kernel, dim3(256), dim3(512), 0, stream,
                       C, out, gpart, nug, cnt);
}